// Round 2
// baseline (1530.228 us; speedup 1.0000x reference)
//
#include <hip/hip_runtime.h>
#include <hip/hip_bf16.h>

// B=512, S=64, IN=128, DM=256, H=8, HD=32, L=2, FF=1024, DO=64, E=8, K=2, GI=8192

typedef __attribute__((ext_vector_type(8))) short bf16x8;
typedef __attribute__((ext_vector_type(4))) float f32x4;

#define DEVINL __device__ __forceinline__
#define MFMA16(a, b, c) __builtin_amdgcn_mfma_f32_16x16x32_bf16((a), (b), (c), 0, 0, 0)

DEVINL float b2f(unsigned short u) {
    unsigned int i = ((unsigned int)u) << 16;
    float f; __builtin_memcpy(&f, &i, 4); return f;
}
DEVINL unsigned short f2b(float f) {
    unsigned int i; __builtin_memcpy(&i, &f, 4);
    unsigned int r = (i + 0x7FFFu + ((i >> 16) & 1u)) >> 16;  // RTN-even
    return (unsigned short)r;
}

// ---------------------------------------------------------------------------
__global__ void zero_cnt_kernel(int* __restrict__ cnt) {
    if (threadIdx.x < 8) cnt[threadIdx.x] = 0;
}

// ---------------------------------------------------------------------------
// convT: src fp32 [batch][R][C] -> dst bf16 [batch][C][R]  (B-operand layout)
__global__ __launch_bounds__(256) void convT_kernel(
    const float* __restrict__ src, short* __restrict__ dst, int R, int C, int total)
{
    int idx = blockIdx.x * 256 + threadIdx.x;
    if (idx >= total) return;
    int rc = R * C;
    int bM = idx / rc;
    int rem = idx - bM * rc;
    int c = rem / R;
    int r = rem - c * R;
    dst[idx] = (short)f2b(src[(size_t)bM * rc + (size_t)r * C + c]);
}

// ---------------------------------------------------------------------------
// gate: double-precision logits (stable top-2 vs numpy ref)
__global__ __launch_bounds__(256) void gate_kernel(
    const float* __restrict__ x, const float* __restrict__ Wg, const float* __restrict__ bg,
    int* __restrict__ cnt, int* __restrict__ rlist, float* __restrict__ wlist)
{
    const int b = blockIdx.x;
    const int tid = threadIdx.x;
    const int e8 = tid & 7;
    const int seg = tid >> 3;
    const float* gi = x + (size_t)b * 8192;
    double p = 0.0;
    for (int ii = 0; ii < 256; ++ii) {
        int i = seg * 256 + ii;
        p += (double)gi[i] * (double)Wg[i * 8 + e8];
    }
    p += __shfl_xor(p, 8, 64);
    p += __shfl_xor(p, 16, 64);
    p += __shfl_xor(p, 32, 64);
    __shared__ double wred[4 * 8];
    const int lane = tid & 63, w = tid >> 6;
    if (lane < 8) wred[w * 8 + lane] = p;
    __syncthreads();
    if (tid == 0) {
        double lg[8];
        for (int e = 0; e < 8; ++e)
            lg[e] = wred[e] + wred[8 + e] + wred[16 + e] + wred[24 + e] + (double)bg[e];
        int i1 = 0;
        for (int e = 1; e < 8; ++e) if (lg[e] > lg[i1]) i1 = e;
        int i2 = (i1 == 0) ? 1 : 0;
        for (int e = 0; e < 8; ++e) if (e != i1 && lg[e] > lg[i2]) i2 = e;
        double ex = exp(lg[i2] - lg[i1]);
        float w1 = (float)(1.0 / (1.0 + ex));
        float w2 = (float)(ex / (1.0 + ex));
        int p1 = atomicAdd(&cnt[i1], 1);
        rlist[i1 * 512 + p1] = b; wlist[i1 * 512 + p1] = w1;
        int p2 = atomicAdd(&cnt[i2], 1);
        rlist[i2 * 512 + p2] = b; wlist[i2 * 512 + p2] = w2;
    }
}

// ---------------------------------------------------------------------------
// resproj: 2 batch rows per block, 256 blocks
__global__ __launch_bounds__(256) void resproj_kernel(
    const float* __restrict__ x, const float* __restrict__ Wr, const float* __restrict__ br,
    float* __restrict__ acc_out)
{
    const int b0 = blockIdx.x * 2;
    const int tid = threadIdx.x;
    const int d = tid & 63;
    const int part = tid >> 6;
    float acc0 = 0.f, acc1 = 0.f;
    for (int ii = 0; ii < 2048; ++ii) {
        int i = part * 2048 + ii;
        float wv = Wr[i * 64 + d];
        acc0 += x[(size_t)b0 * 8192 + i] * wv;
        acc1 += x[(size_t)(b0 + 1) * 8192 + i] * wv;
    }
    __shared__ float rr[4][2][64];
    rr[part][0][d] = acc0;
    rr[part][1][d] = acc1;
    __syncthreads();
    if (tid < 128) {
        int k = tid >> 6, dd = tid & 63;
        float v = rr[0][k][dd] + rr[1][k][dd] + rr[2][k][dd] + rr[3][k][dd];
        acc_out[(b0 + k) * 64 + dd] = 0.1f * (v + br[dd]);
    }
}

// ---------------------------------------------------------------------------
// expert kernel — 512 threads / 8 waves / M-split pairs.
// Wave w = (rh = w>>2, cg = w&3) owns output rows [rh*32, rh*32+32) and
// cols [cg*64, cg*64+64) of every GEMM -> 2 waves/SIMD (was 1).
// __launch_bounds__(512, 1): round 1's (512,2) capped VGPRs at 128 and the
// ~180-live-reg inner loops spilled to scratch (WRITE_SIZE 139MB, MfmaUtil
// 9.5->7.2). Block-fit alone enforces the <=256 VGPR cap for 8 waves.
// XCD pin: e = blockIdx&7 so each XCD's L2 holds one expert's weight image.
__global__ __launch_bounds__(512, 1) void expert_kernel(
    const float* __restrict__ x,
    const short* __restrict__ WinT, const float* __restrict__ bin_,
    const short* __restrict__ WqT,  const float* __restrict__ bq,
    const short* __restrict__ WkT,  const float* __restrict__ bk,
    const short* __restrict__ WvT,  const float* __restrict__ bv,
    const short* __restrict__ WoT,  const float* __restrict__ bo,
    const float* __restrict__ ln1g, const float* __restrict__ ln1b,
    const float* __restrict__ ln2g, const float* __restrict__ ln2b,
    const short* __restrict__ W1T,  const float* __restrict__ b1,
    const short* __restrict__ W2T,  const float* __restrict__ b2,
    const float* __restrict__ Wout, const float* __restrict__ bout,
    const int* __restrict__ cnt, const int* __restrict__ rlist,
    const float* __restrict__ wlist, float* __restrict__ acc_out)
{
    const int e = blockIdx.x & 7;          // XCD pin
    const int s = blockIdx.x >> 3;
    if (s >= cnt[e]) return;
    const int b   = rlist[e * 512 + s];
    const float wgt = wlist[e * 512 + s];
    const int tid = threadIdx.x;
    const int lane = tid & 63;
    const int wg  = __builtin_amdgcn_readfirstlane(tid >> 6);
    const int ln = lane & 15, quad = lane >> 4;
    const int cg = wg & 3;                 // col group: cols [cg*64, +64)
    const int rh = wg >> 2;                // row half:  rows [rh*32, +32)
    const int nb = cg * 64;
    const int r0 = rh * 32;

    // LDS: 33,792 + 96,256 + 2,048 + 2,048 = 134,144 B -> 1 block/CU (8 waves)
    __shared__ __align__(16) unsigned short hS[64 * 264];      // residual/av/LN out
    __shared__ __align__(16) unsigned short attnS[4 * 12032];  // per-pair attn | xS | tS
    __shared__ float redS[512];                                // LN cross-wave partials
    __shared__ float pooledS[512];                             // 2 row-half partials
    unsigned short* Qw  = attnS + cg * 12032;  // [64][40]
    unsigned short* Kw  = Qw + 2560;           // [64][40]
    unsigned short* VTw = Qw + 5120;           // [32][72]
    unsigned short* PSw = Qw + 7424;           // [64][72] (own buffer, no overlay)
    unsigned short* xS  = attnS;               // [64][136] (block-shared, P0/P1)

    // ---- P0: stage x[b] -> xS bf16 row-major ----
    {
        const float* xb = x + (size_t)b * 8192;
        #pragma unroll
        for (int i = 0; i < 16; ++i) {
            int id = tid + 512 * i;
            xS[(id >> 7) * 136 + (id & 127)] = f2b(xb[id]);
        }
    }
    __syncthreads();

    f32x4 hr[8];   // residual: wave's 32 rows x 64 cols, [rt*4+ct]

    // ---- P1: h0 = x @ Win + bin (K=128) ----
    {
        const short* BW = WinT + (size_t)e * 32768;
        const float* bp = bin_ + e * 256;
        bf16x8 Bf[16];
        #pragma unroll
        for (int ct = 0; ct < 4; ++ct)
            #pragma unroll
            for (int kt = 0; kt < 4; ++kt)
                Bf[ct * 4 + kt] = *(const bf16x8*)(BW + (size_t)(nb + ct * 16 + ln) * 128 + kt * 32 + quad * 8);
        float bz[4];
        #pragma unroll
        for (int ct = 0; ct < 4; ++ct) bz[ct] = bp[nb + ct * 16 + ln];
        #pragma unroll
        for (int rt = 0; rt < 2; ++rt) {
            bf16x8 Af[4];
            #pragma unroll
            for (int kt = 0; kt < 4; ++kt)
                Af[kt] = *(const bf16x8*)&xS[(r0 + rt * 16 + ln) * 136 + kt * 32 + quad * 8];
            #pragma unroll
            for (int ct = 0; ct < 4; ++ct) {
                f32x4 c = {bz[ct], bz[ct], bz[ct], bz[ct]};
                #pragma unroll
                for (int kt = 0; kt < 4; ++kt) c = MFMA16(Af[kt], Bf[ct * 4 + kt], c);
                hr[rt * 4 + ct] = c;
                #pragma unroll
                for (int i = 0; i < 4; ++i)
                    hS[(r0 + rt * 16 + quad * 4 + i) * 264 + nb + ct * 16 + ln] = f2b(c[i]);
            }
        }
    }
    __syncthreads();

    // LayerNorm over acc; cross-wave via redS; writes hr + hS.
    auto LN = [&](f32x4* a, const float* g, const float* bb) {
        #pragma unroll
        for (int rt = 0; rt < 2; ++rt)
            #pragma unroll
            for (int i = 0; i < 4; ++i) {
                float s1 = 0.f, s2 = 0.f;
                #pragma unroll
                for (int ct = 0; ct < 4; ++ct) { float v = a[rt * 4 + ct][i]; s1 += v; s2 += v * v; }
                s1 += __shfl_xor(s1, 1); s1 += __shfl_xor(s1, 2);
                s1 += __shfl_xor(s1, 4); s1 += __shfl_xor(s1, 8);
                s2 += __shfl_xor(s2, 1); s2 += __shfl_xor(s2, 2);
                s2 += __shfl_xor(s2, 4); s2 += __shfl_xor(s2, 8);
                if (ln == 0) {
                    int row = r0 + rt * 16 + quad * 4 + i;
                    redS[row * 8 + cg * 2] = s1;
                    redS[row * 8 + cg * 2 + 1] = s2;
                }
            }
        __syncthreads();
        float gv[4], bv2[4];
        #pragma unroll
        for (int ct = 0; ct < 4; ++ct) { gv[ct] = g[nb + ct * 16 + ln]; bv2[ct] = bb[nb + ct * 16 + ln]; }
        #pragma unroll
        for (int rt = 0; rt < 2; ++rt)
            #pragma unroll
            for (int i = 0; i < 4; ++i) {
                int row = r0 + rt * 16 + quad * 4 + i;
                float S1 = redS[row * 8 + 0] + redS[row * 8 + 2] + redS[row * 8 + 4] + redS[row * 8 + 6];
                float S2 = redS[row * 8 + 1] + redS[row * 8 + 3] + redS[row * 8 + 5] + redS[row * 8 + 7];
                float m_ = S1 * (1.f / 256.f);
                float rstd = rsqrtf(S2 * (1.f / 256.f) - m_ * m_ + 1e-5f);
                #pragma unroll
                for (int ct = 0; ct < 4; ++ct) {
                    float v = (a[rt * 4 + ct][i] - m_) * rstd * gv[ct] + bv2[ct];
                    hr[rt * 4 + ct][i] = v;
                    hS[row * 264 + nb + ct * 16 + ln] = f2b(v);
                }
            }
        __syncthreads();
    };

    for (int l = 0; l < 2; ++l) {
        const int el = e * 2 + l;
        const short* WqE = WqT + (size_t)el * 65536;
        const short* WkE = WkT + (size_t)el * 65536;
        const short* WvE = WvT + (size_t)el * 65536;
        const short* WoE = WoT + (size_t)el * 65536;
        const short* W1E = W1T + (size_t)el * 262144;
        const short* W2E = W2T + (size_t)el * 262144;
        const float* bq_p = bq + el * 256;
        const float* bk_p = bk + el * 256;
        const float* bv_p = bv + el * 256;
        const float* bo_p = bo + el * 256;

        f32x4 avr[8];   // both heads' av: [hp*4 + rt*2 + ct2]

        // ---- QKV + attention: pair (rh=0,cg)+(rh=1,cg) shares slot cg ----
        for (int hp = 0; hp < 2; ++hp) {
            const int hb = nb + hp * 32;   // head (2*cg+hp) col base

            auto qkv = [&](const short* WB, const float* bbp, unsigned short* dQK, int isV) {
                bf16x8 Bq[16];
                #pragma unroll
                for (int ct2 = 0; ct2 < 2; ++ct2)
                    #pragma unroll
                    for (int kt = 0; kt < 8; ++kt)
                        Bq[ct2 * 8 + kt] = *(const bf16x8*)(WB + (size_t)(hb + ct2 * 16 + ln) * 256 + kt * 32 + quad * 8);
                float bz2[2];
                #pragma unroll
                for (int ct2 = 0; ct2 < 2; ++ct2) bz2[ct2] = bbp[hb + ct2 * 16 + ln];
                #pragma unroll
                for (int rt = 0; rt < 2; ++rt) {
                    bf16x8 Af[8];
                    #pragma unroll
                    for (int kt = 0; kt < 8; ++kt)
                        Af[kt] = *(const bf16x8*)&hS[(r0 + rt * 16 + ln) * 264 + kt * 32 + quad * 8];
                    #pragma unroll
                    for (int ct2 = 0; ct2 < 2; ++ct2) {
                        f32x4 c = {bz2[ct2], bz2[ct2], bz2[ct2], bz2[ct2]};
                        #pragma unroll
                        for (int kt = 0; kt < 8; ++kt) c = MFMA16(Af[kt], Bq[ct2 * 8 + kt], c);
                        if (!isV) {
                            #pragma unroll
                            for (int i = 0; i < 4; ++i)
                                dQK[(r0 + rt * 16 + quad * 4 + i) * 40 + ct2 * 16 + ln] = f2b(c[i]);
                        } else {
                            #pragma unroll
                            for (int i = 0; i < 4; ++i)
                                VTw[(ct2 * 16 + ln) * 72 + r0 + rt * 16 + quad * 4 + i] = f2b(c[i]);
                        }
                    }
                }
            };
            qkv(WqE, bq_p, Qw, 0);
            qkv(WkE, bk_p, Kw, 0);
            qkv(WvE, bv_p, nullptr, 1);
            __syncthreads();   // pair's K/VT rows complete (also: hS reads done)

            // --- S = Q K^T (M=32 own rows, N=64, K=32) ---
            f32x4 sc[8];
            {
                bf16x8 Bk[4];
                #pragma unroll
                for (int ck = 0; ck < 4; ++ck)
                    Bk[ck] = *(const bf16x8*)&Kw[(ck * 16 + ln) * 40 + quad * 8];
                #pragma unroll
                for (int rt = 0; rt < 2; ++rt) {
                    bf16x8 Aq = *(const bf16x8*)&Qw[(r0 + rt * 16 + ln) * 40 + quad * 8];
                    #pragma unroll
                    for (int ck = 0; ck < 4; ++ck) {
                        f32x4 z = {0.f, 0.f, 0.f, 0.f};
                        sc[rt * 4 + ck] = MFMA16(Aq, Bk[ck], z);
                    }
                }
            }
            // --- softmax per row (in-wave, 16-lane groups) ---
            const float sscale = 0.17677669529663687f;  // 1/sqrt(32)
            #pragma unroll
            for (int t = 0; t < 8; ++t)
                #pragma unroll
                for (int i = 0; i < 4; ++i) sc[t][i] *= sscale;
            #pragma unroll
            for (int rt = 0; rt < 2; ++rt)
                #pragma unroll
                for (int i = 0; i < 4; ++i) {
                    float m_ = fmaxf(fmaxf(sc[rt * 4 + 0][i], sc[rt * 4 + 1][i]),
                                     fmaxf(sc[rt * 4 + 2][i], sc[rt * 4 + 3][i]));
                    m_ = fmaxf(m_, __shfl_xor(m_, 1));
                    m_ = fmaxf(m_, __shfl_xor(m_, 2));
                    m_ = fmaxf(m_, __shfl_xor(m_, 4));
                    m_ = fmaxf(m_, __shfl_xor(m_, 8));
                    float s_ = 0.f;
                    #pragma unroll
                    for (int ck = 0; ck < 4; ++ck) {
                        sc[rt * 4 + ck][i] = __expf(sc[rt * 4 + ck][i] - m_);
                        s_ += sc[rt * 4 + ck][i];
                    }
                    s_ += __shfl_xor(s_, 1); s_ += __shfl_xor(s_, 2);
                    s_ += __shfl_xor(s_, 4); s_ += __shfl_xor(s_, 8);
                    float inv = 1.f / s_;
                    int row = r0 + rt * 16 + quad * 4 + i;
                    #pragma unroll
                    for (int ck = 0; ck < 4; ++ck)
                        PSw[row * 72 + ck * 16 + ln] = f2b(sc[rt * 4 + ck][i] * inv);
                }

            // --- av = P @ V (M=32 own rows, N=32, K=64); PS rows are own-wave ---
            {
                bf16x8 Bv[4];
                #pragma unroll
                for (int ct2 = 0; ct2 < 2; ++ct2)
                    #pragma unroll
                    for (int kt2 = 0; kt2 < 2; ++kt2)
                        Bv[ct2 * 2 + kt2] = *(const bf16x8*)&VTw[(ct2 * 16 + ln) * 72 + kt2 * 32 + quad * 8];
                #pragma unroll
                for (int rt = 0; rt < 2; ++rt) {
                    bf16x8 Ap[2];
                    #pragma unroll
                    for (int kt2 = 0; kt2 < 2; ++kt2)
                        Ap[kt2] = *(const bf16x8*)&PSw[(r0 + rt * 16 + ln) * 72 + kt2 * 32 + quad * 8];
                    #pragma unroll
                    for (int ct2 = 0; ct2 < 2; ++ct2) {
                        f32x4 c = {0.f, 0.f, 0.f, 0.f};
                        #pragma unroll
                        for (int kt2 = 0; kt2 < 2; ++kt2) c = MFMA16(Ap[kt2], Bv[ct2 * 2 + kt2], c);
                        avr[hp * 4 + rt * 2 + ct2] = c;
                    }
                }
            }
            if (hp == 0) __syncthreads();  // partner done reading Kw/VTw before hp=1 overwrites
        }

        // write av (wave's 32 rows x 64 cols) -> hS; hS(h) reads all done at last barrier
        #pragma unroll
        for (int hp = 0; hp < 2; ++hp)
            #pragma unroll
            for (int rt = 0; rt < 2; ++rt)
                #pragma unroll
                for (int ct2 = 0; ct2 < 2; ++ct2)
                    #pragma unroll
                    for (int i = 0; i < 4; ++i)
                        hS[(r0 + rt * 16 + quad * 4 + i) * 264 + nb + hp * 32 + ct2 * 16 + ln]
                            = f2b(avr[hp * 4 + rt * 2 + ct2][i]);
        __syncthreads();

        // ---- O-proj: oacc = h + bo + av @ Wo (K=256); Bo split in 2 halves for VGPR ----
        f32x4 oacc[8];
        #pragma unroll
        for (int rt = 0; rt < 2; ++rt)
            #pragma unroll
            for (int ct = 0; ct < 4; ++ct) {
                float bz = bo_p[nb + ct * 16 + ln];
                f32x4 t = hr[rt * 4 + ct];
                t[0] += bz; t[1] += bz; t[2] += bz; t[3] += bz;
                oacc[rt * 4 + ct] = t;
            }
        #pragma unroll
        for (int ch2 = 0; ch2 < 2; ++ch2) {
            bf16x8 Bo[16];
            #pragma unroll
            for (int ctl = 0; ctl < 2; ++ctl)
                #pragma unroll
                for (int kt = 0; kt < 8; ++kt)
                    Bo[ctl * 8 + kt] = *(const bf16x8*)(WoE + (size_t)(nb + (ch2 * 2 + ctl) * 16 + ln) * 256 + kt * 32 + quad * 8);
            #pragma unroll
            for (int rt = 0; rt < 2; ++rt) {
                bf16x8 Af[8];
                #pragma unroll
                for (int kt = 0; kt < 8; ++kt)
                    Af[kt] = *(const bf16x8*)&hS[(r0 + rt * 16 + ln) * 264 + kt * 32 + quad * 8];
                #pragma unroll
                for (int ctl = 0; ctl < 2; ++ctl)
                    #pragma unroll
                    for (int kt = 0; kt < 8; ++kt)
                        oacc[rt * 4 + ch2 * 2 + ctl] = MFMA16(Af[kt], Bo[ctl * 8 + kt], oacc[rt * 4 + ch2 * 2 + ctl]);
            }
        }

        // ---- LN1 -> hr, hS ----
        LN(oacc, ln1g + el * 256, ln1b + el * 256);

        // ---- FF: 8 chunks of 128 FF cols, tS double-buffered (1 barrier/chunk) ----
        f32x4 facc[8];
        {
            const float* b2_p = b2 + el * 256;
            #pragma unroll
            for (int rt = 0; rt < 2; ++rt)
                #pragma unroll
                for (int ct = 0; ct < 4; ++ct) {
                    float bz = b2_p[nb + ct * 16 + ln];
                    f32x4 t = hr[rt * 4 + ct];
                    t[0] += bz; t[1] += bz; t[2] += bz; t[3] += bz;
                    facc[rt * 4 + ct] = t;
                }
        }
        const float* b1_p = b1 + el * 1024;
        for (int ch = 0; ch < 8; ++ch) {
            const int fb = ch * 128 + cg * 32;       // wave's 32 FF cols this chunk
            unsigned short* tC = attnS + (ch & 1) * 8704;   // [64][136] dbuf
            {
                bf16x8 B1[16];
                #pragma unroll
                for (int ct2 = 0; ct2 < 2; ++ct2)
                    #pragma unroll
                    for (int kt = 0; kt < 8; ++kt)
                        B1[ct2 * 8 + kt] = *(const bf16x8*)(W1E + (size_t)(fb + ct2 * 16 + ln) * 256 + kt * 32 + quad * 8);
                float bz2[2];
                #pragma unroll
                for (int ct2 = 0; ct2 < 2; ++ct2) bz2[ct2] = b1_p[fb + ct2 * 16 + ln];
                #pragma unroll
                for (int rt = 0; rt < 2; ++rt) {
                    bf16x8 Af[8];
                    #pragma unroll
                    for (int kt = 0; kt < 8; ++kt)
                        Af[kt] = *(const bf16x8*)&hS[(r0 + rt * 16 + ln) * 264 + kt * 32 + quad * 8];
                    #pragma unroll
                    for (int ct2 = 0; ct2 < 2; ++ct2) {
                        f32x4 c = {bz2[ct2], bz2[ct2], bz2[ct2], bz2[ct2]};
                        #pragma unroll
                        for (int kt = 0; kt < 8; ++kt) c = MFMA16(Af[kt], B1[ct2 * 8 + kt], c);
                        #pragma unroll
                        for (int i = 0; i < 4; ++i)
                            tC[(r0 + rt * 16 + quad * 4 + i) * 136 + cg * 32 + ct2 * 16 + ln]
                                = f2b(fmaxf(c[i], 0.f));
                    }
                }
            }
            __syncthreads();
            // W2 partial: K=128 (reads own rows, all cg strips of tC)
            {
                bf16x8 B2[16];
                #pragma unroll
                for (int ct = 0; ct < 4; ++ct)
                    #pragma unroll
                    for (int kt2 = 0; kt2 < 4; ++kt2)
                        B2[ct * 4 + kt2] = *(const bf16x8*)(W2E + (size_t)(nb + ct * 16 + ln) * 1024 + ch * 128 + kt2 * 32 + quad * 8);
                #pragma unroll
                for (int rt = 0; rt < 2; ++rt) {
                    bf16x8 At[4];
                    #pragma unroll
                    for (int kt2 = 0; kt2 < 4; ++kt2)
                        At[kt2] = *(const bf16x8*)&tC[(r0 + rt * 16 + ln) * 136 + kt2 * 32 + quad * 8];
                    #pragma unroll
                    for (int ct = 0; ct < 4; ++ct)
                        #pragma unroll
                        for (int kt2 = 0; kt2 < 4; ++kt2)
                            facc[rt * 4 + ct] = MFMA16(At[kt2], B2[ct * 4 + kt2], facc[rt * 4 + ct]);
                }
            }
            // no barrier: next W1 writes the other tS buffer
        }

        // ---- LN2 -> hr, hS ----
        LN(facc, ln2g + el * 256, ln2b + el * 256);
    }

    // ---- pooling + Wout + weighted combine ----
    {
        #pragma unroll
        for (int ct = 0; ct < 4; ++ct) {
            float s_ = 0.f;
            #pragma unroll
            for (int rt = 0; rt < 2; ++rt)
                #pragma unroll
                for (int i = 0; i < 4; ++i) s_ += hr[rt * 4 + ct][i];
            s_ += __shfl_xor(s_, 16);
            s_ += __shfl_xor(s_, 32);
            if (quad == 0) pooledS[rh * 256 + nb + ct * 16 + ln] = s_;
        }
        __syncthreads();
        if (tid < 64) {
            const float* Wout_p = Wout + (size_t)e * (256 * 64);
            float o = bout[e * 64 + tid];
            for (int c = 0; c < 256; ++c)
                o += (pooledS[c] + pooledS[256 + c]) * (1.f / 64.f) * Wout_p[c * 64 + tid];
            atomicAdd(&acc_out[b * 64 + tid], wgt * o);
        }
    }
}

// ---------------------------------------------------------------------------
__global__ __launch_bounds__(64) void final_ln_kernel(
    const float* __restrict__ acc_out, const float* __restrict__ on_g,
    const float* __restrict__ on_b, float* __restrict__ out)
{
    const int b = blockIdx.x;
    const int d = threadIdx.x;
    float v = acc_out[b * 64 + d];
    float s1 = v, s2 = v * v;
    #pragma unroll
    for (int st = 1; st < 64; st <<= 1) {
        s1 += __shfl_xor(s1, st, 64);
        s2 += __shfl_xor(s2, st, 64);
    }
    float m   = s1 * (1.f / 64.f);
    float var = s2 * (1.f / 64.f) - m * m;
    float rstd = rsqrtf(var + 1e-5f);
    out[b * 64 + d] = (v - m) * rstd * on_g[d] + on_b[d];
}

// ---------------------------------------------------------------------------
extern "C" void kernel_launch(void* const* d_in, const int* in_sizes, int n_in,
                              void* d_out, int out_size, void* d_ws, size_t ws_size,
                              hipStream_t stream)
{
    (void)in_sizes; (void)n_in; (void)out_size; (void)ws_size;
    const float* x    = (const float*)d_in[0];
    const float* Win  = (const float*)d_in[1];
    const float* bin_ = (const float*)d_in[2];
    const float* Wq   = (const float*)d_in[3];
    const float* bq   = (const float*)d_in[4];
    const float* Wk   = (const float*)d_in[5];
    const float* bk   = (const float*)d_in[6];
    const float* Wv   = (const float*)d_in[7];
    const float* bv   = (const float*)d_in[8];
    const float* Wo   = (const float*)d_in[9];
    const float* bo   = (const float*)d_in[10];
    const float* ln1g = (const float*)d_in[11];
    const float* ln1b = (const float*)d_in[12];
    const float* ln2g = (const float*)d_in[13];
    const float* ln2b = (const float*)d_in[14];
    const float* W1   = (const float*)d_in[15];
    const float* b1   = (const float*)d_in[16];
    const float* W2   = (const float*)d_in[17];
    const float* b2   = (const float*)d_in[18];
    const float* Wout = (const float*)d_in[19];
    const float* bout = (const float*)d_in[20];
    const float* Wg   = (const float*)d_in[21];
    const float* bg   = (const float*)d_in[22];
    const float* Wr   = (const float*)d_in[23];
    const float* br   = (const float*)d_in[24];
    const float* on_g = (const float*)d_in[25];
    const float* on_b = (const float*)d_in[26];
    float* out = (float*)d_out;

    // workspace carve-up
    char* ws = (char*)d_ws;
    float* acc_out = (float*)ws;                         // 131,072 B
    int*   cnt     = (int*)(ws + 131072);
    int*   rlist   = (int*)(ws + 131200);                // 16,384 B
    float* wlist   = (float*)(ws + 147584);              // 16,384 B
    short* WinT    = (short*)(ws + 164096);              //   524,288 B
    short* WqT     = (short*)(ws + 688384);              // 2,097,152 B
    short* WkT     = (short*)(ws + 2785536);
    short* WvT     = (short*)(ws + 4882688);
    short* WoT     = (short*)(ws + 6979840);
    short* W1T     = (short*)(ws + 9076992);             // 8,388,608 B
    short* W2T     = (short*)(ws + 17465600);            // 8,388,608 B

    // weight transposition fp32 [R][C] -> bf16 [C][R]
    convT_kernel<<<1024, 256, 0, stream>>>(Win, WinT, 128, 256, 262144);
    convT_kernel<<<4096, 256, 0, stream>>>(Wq, WqT, 256, 256, 1048576);
    convT_kernel<<<4096, 256, 0, stream>>>(Wk, WkT, 256, 256, 1048576);
    convT_kernel<<<4096, 256, 0, stream>>>(Wv, WvT, 256, 256, 1048576);
    convT_kernel<<<4096, 256, 0, stream>>>(Wo, WoT, 256, 256, 1048576);
    convT_kernel<<<16384, 256, 0, stream>>>(W1, W1T, 256, 1024, 4194304);
    convT_kernel<<<16384, 256, 0, stream>>>(W2, W2T, 1024, 256, 4194304);

    zero_cnt_kernel<<<1, 64, 0, stream>>>(cnt);
    gate_kernel<<<512, 256, 0, stream>>>(x, Wg, bg, cnt, rlist, wlist);
    resproj_kernel<<<256, 256, 0, stream>>>(x, Wr, br, acc_out);
    expert_kernel<<<4096, 512, 0, stream>>>(x,
        WinT, bin_, WqT, bq, WkT, bk, WvT, bv, WoT, bo,
        ln1g, ln1b, ln2g, ln2b, W1T, b1, W2T, b2, Wout, bout,
        cnt, rlist, wlist, acc_out);
    final_ln_kernel<<<512, 64, 0, stream>>>(acc_out, on_g, on_b, out);
}

// Round 4
// 1449.787 us; speedup vs baseline: 1.0555x; 1.0555x over previous
//
#include <hip/hip_runtime.h>
#include <hip/hip_bf16.h>

// B=512, S=64, IN=128, DM=256, H=8, HD=32, L=2, FF=1024, DO=64, E=8, K=2, GI=8192

typedef __attribute__((ext_vector_type(8))) short bf16x8;
typedef __attribute__((ext_vector_type(4))) float f32x4;

#define DEVINL __device__ __forceinline__
#define MFMA16(a, b, c) __builtin_amdgcn_mfma_f32_16x16x32_bf16((a), (b), (c), 0, 0, 0)

DEVINL float b2f(unsigned short u) {
    unsigned int i = ((unsigned int)u) << 16;
    float f; __builtin_memcpy(&f, &i, 4); return f;
}
DEVINL unsigned short f2b(float f) {
    unsigned int i; __builtin_memcpy(&i, &f, 4);
    unsigned int r = (i + 0x7FFFu + ((i >> 16) & 1u)) >> 16;  // RTN-even
    return (unsigned short)r;
}

// ---------------------------------------------------------------------------
__global__ void zero_cnt_kernel(int* __restrict__ cnt) {
    if (threadIdx.x < 8) cnt[threadIdx.x] = 0;
}

// ---------------------------------------------------------------------------
// convT: src fp32 [batch][R][C] -> dst bf16 [batch][C][R]  (B-operand layout)
__global__ __launch_bounds__(256) void convT_kernel(
    const float* __restrict__ src, short* __restrict__ dst, int R, int C, int total)
{
    int idx = blockIdx.x * 256 + threadIdx.x;
    if (idx >= total) return;
    int rc = R * C;
    int bM = idx / rc;
    int rem = idx - bM * rc;
    int c = rem / R;
    int r = rem - c * R;
    dst[idx] = (short)f2b(src[(size_t)bM * rc + (size_t)r * C + c]);
}

// ---------------------------------------------------------------------------
// gate: double-precision logits (stable top-2 vs numpy ref)
__global__ __launch_bounds__(256) void gate_kernel(
    const float* __restrict__ x, const float* __restrict__ Wg, const float* __restrict__ bg,
    int* __restrict__ cnt, int* __restrict__ rlist, float* __restrict__ wlist)
{
    const int b = blockIdx.x;
    const int tid = threadIdx.x;
    const int e8 = tid & 7;
    const int seg = tid >> 3;
    const float* gi = x + (size_t)b * 8192;
    double p = 0.0;
    for (int ii = 0; ii < 256; ++ii) {
        int i = seg * 256 + ii;
        p += (double)gi[i] * (double)Wg[i * 8 + e8];
    }
    p += __shfl_xor(p, 8, 64);
    p += __shfl_xor(p, 16, 64);
    p += __shfl_xor(p, 32, 64);
    __shared__ double wred[4 * 8];
    const int lane = tid & 63, w = tid >> 6;
    if (lane < 8) wred[w * 8 + lane] = p;
    __syncthreads();
    if (tid == 0) {
        double lg[8];
        for (int e = 0; e < 8; ++e)
            lg[e] = wred[e] + wred[8 + e] + wred[16 + e] + wred[24 + e] + (double)bg[e];
        int i1 = 0;
        for (int e = 1; e < 8; ++e) if (lg[e] > lg[i1]) i1 = e;
        int i2 = (i1 == 0) ? 1 : 0;
        for (int e = 0; e < 8; ++e) if (e != i1 && lg[e] > lg[i2]) i2 = e;
        double ex = exp(lg[i2] - lg[i1]);
        float w1 = (float)(1.0 / (1.0 + ex));
        float w2 = (float)(ex / (1.0 + ex));
        int p1 = atomicAdd(&cnt[i1], 1);
        rlist[i1 * 512 + p1] = b; wlist[i1 * 512 + p1] = w1;
        int p2 = atomicAdd(&cnt[i2], 1);
        rlist[i2 * 512 + p2] = b; wlist[i2 * 512 + p2] = w2;
    }
}

// ---------------------------------------------------------------------------
// resproj: 2 batch rows per block, 256 blocks
__global__ __launch_bounds__(256) void resproj_kernel(
    const float* __restrict__ x, const float* __restrict__ Wr, const float* __restrict__ br,
    float* __restrict__ acc_out)
{
    const int b0 = blockIdx.x * 2;
    const int tid = threadIdx.x;
    const int d = tid & 63;
    const int part = tid >> 6;
    float acc0 = 0.f, acc1 = 0.f;
    for (int ii = 0; ii < 2048; ++ii) {
        int i = part * 2048 + ii;
        float wv = Wr[i * 64 + d];
        acc0 += x[(size_t)b0 * 8192 + i] * wv;
        acc1 += x[(size_t)(b0 + 1) * 8192 + i] * wv;
    }
    __shared__ float rr[4][2][64];
    rr[part][0][d] = acc0;
    rr[part][1][d] = acc1;
    __syncthreads();
    if (tid < 128) {
        int k = tid >> 6, dd = tid & 63;
        float v = rr[0][k][dd] + rr[1][k][dd] + rr[2][k][dd] + rr[3][k][dd];
        acc_out[(b0 + k) * 64 + dd] = 0.1f * (v + br[dd]);
    }
}

// ---------------------------------------------------------------------------
// expert kernel — 512 threads / 8 waves / M-split pairs.
// Wave w = (rh = w>>2, cg = w&3) owns output rows [rh*32, +32) and cols
// [cg*64, +64) of every GEMM -> 2 waves/SIMD.
// ROUND 3 (resubmit; round-3 bench was an infra failure): 512-thread flat
// size forces total (arch+acc) regs <= 256; the allocator gives the arch
// class 128. Rounds 1-2 had ~180 arch-live in hot loops -> 139MB scratch
// spills. Fix: arch working set < 128 by (a) hoisting A-frags ONCE per
// phase (same hS rows feed Q,K,V and all 8 FF-W1 chunks), (b) chunking
// B-frag batches 16->8/4. Peak arch live ~111.
// XCD pin: e = blockIdx&7 so each XCD's L2 holds one expert's weight image.
__global__ __launch_bounds__(512, 1) void expert_kernel(
    const float* __restrict__ x,
    const short* __restrict__ WinT, const float* __restrict__ bin_,
    const short* __restrict__ WqT,  const float* __restrict__ bq,
    const short* __restrict__ WkT,  const float* __restrict__ bk,
    const short* __restrict__ WvT,  const float* __restrict__ bv,
    const short* __restrict__ WoT,  const float* __restrict__ bo,
    const float* __restrict__ ln1g, const float* __restrict__ ln1b,
    const float* __restrict__ ln2g, const float* __restrict__ ln2b,
    const short* __restrict__ W1T,  const float* __restrict__ b1,
    const short* __restrict__ W2T,  const float* __restrict__ b2,
    const float* __restrict__ Wout, const float* __restrict__ bout,
    const int* __restrict__ cnt, const int* __restrict__ rlist,
    const float* __restrict__ wlist, float* __restrict__ acc_out)
{
    const int e = blockIdx.x & 7;          // XCD pin
    const int s = blockIdx.x >> 3;
    if (s >= cnt[e]) return;
    const int b   = rlist[e * 512 + s];
    const float wgt = wlist[e * 512 + s];
    const int tid = threadIdx.x;
    const int lane = tid & 63;
    const int wg  = __builtin_amdgcn_readfirstlane(tid >> 6);
    const int ln = lane & 15, quad = lane >> 4;
    const int cg = wg & 3;                 // col group: cols [cg*64, +64)
    const int rh = wg >> 2;                // row half:  rows [rh*32, +32)
    const int nb = cg * 64;
    const int r0 = rh * 32;

    // LDS: 33,792 + 96,256 + 2,048 + 2,048 = 134,144 B -> 1 block/CU (8 waves)
    __shared__ __align__(16) unsigned short hS[64 * 264];      // residual/av/LN out
    __shared__ __align__(16) unsigned short attnS[4 * 12032];  // per-pair attn | xS | tS
    __shared__ float redS[512];                                // LN cross-wave partials
    __shared__ float pooledS[512];                             // 2 row-half partials
    unsigned short* Qw  = attnS + cg * 12032;  // [64][40]
    unsigned short* Kw  = Qw + 2560;           // [64][40]
    unsigned short* VTw = Qw + 5120;           // [32][72]
    unsigned short* PSw = Qw + 7424;           // [64][72] (own buffer, no overlay)
    unsigned short* xS  = attnS;               // [64][136] (block-shared, P0/P1)

    // ---- P0: stage x[b] -> xS bf16 row-major ----
    {
        const float* xb = x + (size_t)b * 8192;
        #pragma unroll
        for (int i = 0; i < 16; ++i) {
            int id = tid + 512 * i;
            xS[(id >> 7) * 136 + (id & 127)] = f2b(xb[id]);
        }
    }
    __syncthreads();

    f32x4 hr[8];   // residual: wave's 32 rows x 64 cols, [rt*4+ct]

    // ---- P1: h0 = x @ Win + bin (K=128) ----
    {
        const short* BW = WinT + (size_t)e * 32768;
        const float* bp = bin_ + e * 256;
        bf16x8 Af[8];
        #pragma unroll
        for (int rt = 0; rt < 2; ++rt)
            #pragma unroll
            for (int kt = 0; kt < 4; ++kt)
                Af[rt * 4 + kt] = *(const bf16x8*)&xS[(r0 + rt * 16 + ln) * 136 + kt * 32 + quad * 8];
        #pragma unroll
        for (int ct = 0; ct < 4; ++ct) {
            bf16x8 Bf[4];
            #pragma unroll
            for (int kt = 0; kt < 4; ++kt)
                Bf[kt] = *(const bf16x8*)(BW + (size_t)(nb + ct * 16 + ln) * 128 + kt * 32 + quad * 8);
            float bz = bp[nb + ct * 16 + ln];
            #pragma unroll
            for (int rt = 0; rt < 2; ++rt) {
                f32x4 c = {bz, bz, bz, bz};
                #pragma unroll
                for (int kt = 0; kt < 4; ++kt) c = MFMA16(Af[rt * 4 + kt], Bf[kt], c);
                hr[rt * 4 + ct] = c;
                #pragma unroll
                for (int i = 0; i < 4; ++i)
                    hS[(r0 + rt * 16 + quad * 4 + i) * 264 + nb + ct * 16 + ln] = f2b(c[i]);
            }
        }
    }
    __syncthreads();

    // LayerNorm over acc; cross-wave via redS; writes hr + hS.
    auto LN = [&](f32x4* a, const float* g, const float* bb) {
        #pragma unroll
        for (int rt = 0; rt < 2; ++rt)
            #pragma unroll
            for (int i = 0; i < 4; ++i) {
                float s1 = 0.f, s2 = 0.f;
                #pragma unroll
                for (int ct = 0; ct < 4; ++ct) { float v = a[rt * 4 + ct][i]; s1 += v; s2 += v * v; }
                s1 += __shfl_xor(s1, 1); s1 += __shfl_xor(s1, 2);
                s1 += __shfl_xor(s1, 4); s1 += __shfl_xor(s1, 8);
                s2 += __shfl_xor(s2, 1); s2 += __shfl_xor(s2, 2);
                s2 += __shfl_xor(s2, 4); s2 += __shfl_xor(s2, 8);
                if (ln == 0) {
                    int row = r0 + rt * 16 + quad * 4 + i;
                    redS[row * 8 + cg * 2] = s1;
                    redS[row * 8 + cg * 2 + 1] = s2;
                }
            }
        __syncthreads();
        float gv[4], bv2[4];
        #pragma unroll
        for (int ct = 0; ct < 4; ++ct) { gv[ct] = g[nb + ct * 16 + ln]; bv2[ct] = bb[nb + ct * 16 + ln]; }
        #pragma unroll
        for (int rt = 0; rt < 2; ++rt)
            #pragma unroll
            for (int i = 0; i < 4; ++i) {
                int row = r0 + rt * 16 + quad * 4 + i;
                float S1 = redS[row * 8 + 0] + redS[row * 8 + 2] + redS[row * 8 + 4] + redS[row * 8 + 6];
                float S2 = redS[row * 8 + 1] + redS[row * 8 + 3] + redS[row * 8 + 5] + redS[row * 8 + 7];
                float m_ = S1 * (1.f / 256.f);
                float rstd = rsqrtf(S2 * (1.f / 256.f) - m_ * m_ + 1e-5f);
                #pragma unroll
                for (int ct = 0; ct < 4; ++ct) {
                    float v = (a[rt * 4 + ct][i] - m_) * rstd * gv[ct] + bv2[ct];
                    hr[rt * 4 + ct][i] = v;
                    hS[row * 264 + nb + ct * 16 + ln] = f2b(v);
                }
            }
        __syncthreads();
    };

    for (int l = 0; l < 2; ++l) {
        const int el = e * 2 + l;
        const short* WqE = WqT + (size_t)el * 65536;
        const short* WkE = WkT + (size_t)el * 65536;
        const short* WvE = WvT + (size_t)el * 65536;
        const short* WoE = WoT + (size_t)el * 65536;
        const short* W1E = W1T + (size_t)el * 262144;
        const short* W2E = W2T + (size_t)el * 262144;
        const float* bq_p = bq + el * 256;
        const float* bk_p = bk + el * 256;
        const float* bv_p = bv + el * 256;
        const float* bo_p = bo + el * 256;

        f32x4 avr[8];   // both heads' av: [hp*4 + rt*2 + ct2]

        // ---- QKV + attention: pair (rh=0,cg)+(rh=1,cg) shares slot cg ----
        // A-frags hoisted ONCE: same hS rows feed Q,K,V for both heads.
        bf16x8 Ah[16];
        #pragma unroll
        for (int rt = 0; rt < 2; ++rt)
            #pragma unroll
            for (int kt = 0; kt < 8; ++kt)
                Ah[rt * 8 + kt] = *(const bf16x8*)&hS[(r0 + rt * 16 + ln) * 264 + kt * 32 + quad * 8];

        for (int hp = 0; hp < 2; ++hp) {
            const int hb = nb + hp * 32;   // head (2*cg+hp) col base

            auto qkv = [&](const short* WB, const float* bbp, unsigned short* dQK, int isV) {
                #pragma unroll
                for (int ct2 = 0; ct2 < 2; ++ct2) {
                    bf16x8 Bq[8];
                    #pragma unroll
                    for (int kt = 0; kt < 8; ++kt)
                        Bq[kt] = *(const bf16x8*)(WB + (size_t)(hb + ct2 * 16 + ln) * 256 + kt * 32 + quad * 8);
                    const float bz2 = bbp[hb + ct2 * 16 + ln];
                    #pragma unroll
                    for (int rt = 0; rt < 2; ++rt) {
                        f32x4 c = {bz2, bz2, bz2, bz2};
                        #pragma unroll
                        for (int kt = 0; kt < 8; ++kt) c = MFMA16(Ah[rt * 8 + kt], Bq[kt], c);
                        if (!isV) {
                            #pragma unroll
                            for (int i = 0; i < 4; ++i)
                                dQK[(r0 + rt * 16 + quad * 4 + i) * 40 + ct2 * 16 + ln] = f2b(c[i]);
                        } else {
                            #pragma unroll
                            for (int i = 0; i < 4; ++i)
                                VTw[(ct2 * 16 + ln) * 72 + r0 + rt * 16 + quad * 4 + i] = f2b(c[i]);
                        }
                    }
                }
            };
            qkv(WqE, bq_p, Qw, 0);
            qkv(WkE, bk_p, Kw, 0);
            qkv(WvE, bv_p, nullptr, 1);
            __syncthreads();   // pair's K/VT rows complete (also: hS reads done)

            // --- S = Q K^T (M=32 own rows, N=64, K=32) ---
            f32x4 sc[8];
            {
                bf16x8 Bk[4];
                #pragma unroll
                for (int ck = 0; ck < 4; ++ck)
                    Bk[ck] = *(const bf16x8*)&Kw[(ck * 16 + ln) * 40 + quad * 8];
                #pragma unroll
                for (int rt = 0; rt < 2; ++rt) {
                    bf16x8 Aq = *(const bf16x8*)&Qw[(r0 + rt * 16 + ln) * 40 + quad * 8];
                    #pragma unroll
                    for (int ck = 0; ck < 4; ++ck) {
                        f32x4 z = {0.f, 0.f, 0.f, 0.f};
                        sc[rt * 4 + ck] = MFMA16(Aq, Bk[ck], z);
                    }
                }
            }
            // --- softmax per row (in-wave, 16-lane groups) ---
            const float sscale = 0.17677669529663687f;  // 1/sqrt(32)
            #pragma unroll
            for (int t = 0; t < 8; ++t)
                #pragma unroll
                for (int i = 0; i < 4; ++i) sc[t][i] *= sscale;
            #pragma unroll
            for (int rt = 0; rt < 2; ++rt)
                #pragma unroll
                for (int i = 0; i < 4; ++i) {
                    float m_ = fmaxf(fmaxf(sc[rt * 4 + 0][i], sc[rt * 4 + 1][i]),
                                     fmaxf(sc[rt * 4 + 2][i], sc[rt * 4 + 3][i]));
                    m_ = fmaxf(m_, __shfl_xor(m_, 1));
                    m_ = fmaxf(m_, __shfl_xor(m_, 2));
                    m_ = fmaxf(m_, __shfl_xor(m_, 4));
                    m_ = fmaxf(m_, __shfl_xor(m_, 8));
                    float s_ = 0.f;
                    #pragma unroll
                    for (int ck = 0; ck < 4; ++ck) {
                        sc[rt * 4 + ck][i] = __expf(sc[rt * 4 + ck][i] - m_);
                        s_ += sc[rt * 4 + ck][i];
                    }
                    s_ += __shfl_xor(s_, 1); s_ += __shfl_xor(s_, 2);
                    s_ += __shfl_xor(s_, 4); s_ += __shfl_xor(s_, 8);
                    float inv = 1.f / s_;
                    int row = r0 + rt * 16 + quad * 4 + i;
                    #pragma unroll
                    for (int ck = 0; ck < 4; ++ck)
                        PSw[row * 72 + ck * 16 + ln] = f2b(sc[rt * 4 + ck][i] * inv);
                }

            // --- av = P @ V (M=32 own rows, N=32, K=64); PS rows are own-wave ---
            {
                bf16x8 Bv[4];
                #pragma unroll
                for (int ct2 = 0; ct2 < 2; ++ct2)
                    #pragma unroll
                    for (int kt2 = 0; kt2 < 2; ++kt2)
                        Bv[ct2 * 2 + kt2] = *(const bf16x8*)&VTw[(ct2 * 16 + ln) * 72 + kt2 * 32 + quad * 8];
                #pragma unroll
                for (int rt = 0; rt < 2; ++rt) {
                    bf16x8 Ap[2];
                    #pragma unroll
                    for (int kt2 = 0; kt2 < 2; ++kt2)
                        Ap[kt2] = *(const bf16x8*)&PSw[(r0 + rt * 16 + ln) * 72 + kt2 * 32 + quad * 8];
                    #pragma unroll
                    for (int ct2 = 0; ct2 < 2; ++ct2) {
                        f32x4 c = {0.f, 0.f, 0.f, 0.f};
                        #pragma unroll
                        for (int kt2 = 0; kt2 < 2; ++kt2) c = MFMA16(Ap[kt2], Bv[ct2 * 2 + kt2], c);
                        avr[hp * 4 + rt * 2 + ct2] = c;
                    }
                }
            }
            if (hp == 0) __syncthreads();  // partner done reading Kw/VTw before hp=1 overwrites
        }

        // write av (wave's 32 rows x 64 cols) -> hS; hS(h) reads all done at last barrier
        #pragma unroll
        for (int hp = 0; hp < 2; ++hp)
            #pragma unroll
            for (int rt = 0; rt < 2; ++rt)
                #pragma unroll
                for (int ct2 = 0; ct2 < 2; ++ct2)
                    #pragma unroll
                    for (int i = 0; i < 4; ++i)
                        hS[(r0 + rt * 16 + quad * 4 + i) * 264 + nb + hp * 32 + ct2 * 16 + ln]
                            = f2b(avr[hp * 4 + rt * 2 + ct2][i]);
        __syncthreads();

        // ---- O-proj: oacc = h + bo + av @ Wo (K=256) ----
        // A hoisted once (16 frags); B streamed 8-frag chunks per col tile.
        f32x4 oacc[8];
        #pragma unroll
        for (int rt = 0; rt < 2; ++rt)
            #pragma unroll
            for (int ct = 0; ct < 4; ++ct) {
                float bz = bo_p[nb + ct * 16 + ln];
                f32x4 t = hr[rt * 4 + ct];
                t[0] += bz; t[1] += bz; t[2] += bz; t[3] += bz;
                oacc[rt * 4 + ct] = t;
            }
        {
            bf16x8 Ao[16];
            #pragma unroll
            for (int rt = 0; rt < 2; ++rt)
                #pragma unroll
                for (int kt = 0; kt < 8; ++kt)
                    Ao[rt * 8 + kt] = *(const bf16x8*)&hS[(r0 + rt * 16 + ln) * 264 + kt * 32 + quad * 8];
            #pragma unroll
            for (int ct = 0; ct < 4; ++ct) {
                bf16x8 Bo[8];
                #pragma unroll
                for (int kt = 0; kt < 8; ++kt)
                    Bo[kt] = *(const bf16x8*)(WoE + (size_t)(nb + ct * 16 + ln) * 256 + kt * 32 + quad * 8);
                #pragma unroll
                for (int rt = 0; rt < 2; ++rt)
                    #pragma unroll
                    for (int kt = 0; kt < 8; ++kt)
                        oacc[rt * 4 + ct] = MFMA16(Ao[rt * 8 + kt], Bo[kt], oacc[rt * 4 + ct]);
            }
        }

        // ---- LN1 -> hr, hS ----
        LN(oacc, ln1g + el * 256, ln1b + el * 256);

        // ---- FF: 8 chunks of 128 FF cols, tS double-buffered (1 barrier/chunk) ----
        f32x4 facc[8];
        {
            const float* b2_p = b2 + el * 256;
            #pragma unroll
            for (int rt = 0; rt < 2; ++rt)
                #pragma unroll
                for (int ct = 0; ct < 4; ++ct) {
                    float bz = b2_p[nb + ct * 16 + ln];
                    f32x4 t = hr[rt * 4 + ct];
                    t[0] += bz; t[1] += bz; t[2] += bz; t[3] += bz;
                    facc[rt * 4 + ct] = t;
                }
        }
        // A-frags (post-LN1 h) hoisted once for ALL 8 W1 chunks
        bf16x8 Ah3[16];
        #pragma unroll
        for (int rt = 0; rt < 2; ++rt)
            #pragma unroll
            for (int kt = 0; kt < 8; ++kt)
                Ah3[rt * 8 + kt] = *(const bf16x8*)&hS[(r0 + rt * 16 + ln) * 264 + kt * 32 + quad * 8];
        const float* b1_p = b1 + el * 1024;
        for (int ch = 0; ch < 8; ++ch) {
            const int fb = ch * 128 + cg * 32;       // wave's 32 FF cols this chunk
            unsigned short* tC = attnS + (ch & 1) * 8704;   // [64][136] dbuf
            #pragma unroll
            for (int ct2 = 0; ct2 < 2; ++ct2) {
                bf16x8 B1c[8];
                #pragma unroll
                for (int kt = 0; kt < 8; ++kt)
                    B1c[kt] = *(const bf16x8*)(W1E + (size_t)(fb + ct2 * 16 + ln) * 256 + kt * 32 + quad * 8);
                const float bz2 = b1_p[fb + ct2 * 16 + ln];
                #pragma unroll
                for (int rt = 0; rt < 2; ++rt) {
                    f32x4 c = {bz2, bz2, bz2, bz2};
                    #pragma unroll
                    for (int kt = 0; kt < 8; ++kt) c = MFMA16(Ah3[rt * 8 + kt], B1c[kt], c);
                    #pragma unroll
                    for (int i = 0; i < 4; ++i)
                        tC[(r0 + rt * 16 + quad * 4 + i) * 136 + cg * 32 + ct2 * 16 + ln]
                            = f2b(fmaxf(c[i], 0.f));
                }
            }
            __syncthreads();
            // W2 partial: K=128 (reads own rows, all cg strips of tC)
            #pragma unroll
            for (int rt = 0; rt < 2; ++rt) {
                bf16x8 At[4];
                #pragma unroll
                for (int kt2 = 0; kt2 < 4; ++kt2)
                    At[kt2] = *(const bf16x8*)&tC[(r0 + rt * 16 + ln) * 136 + kt2 * 32 + quad * 8];
                #pragma unroll
                for (int ct = 0; ct < 4; ++ct) {
                    bf16x8 B2c[4];
                    #pragma unroll
                    for (int kt2 = 0; kt2 < 4; ++kt2)
                        B2c[kt2] = *(const bf16x8*)(W2E + (size_t)(nb + ct * 16 + ln) * 1024 + ch * 128 + kt2 * 32 + quad * 8);
                    #pragma unroll
                    for (int kt2 = 0; kt2 < 4; ++kt2)
                        facc[rt * 4 + ct] = MFMA16(At[kt2], B2c[kt2], facc[rt * 4 + ct]);
                }
            }
            // no barrier: next W1 writes the other tS buffer
        }

        // ---- LN2 -> hr, hS ----
        LN(facc, ln2g + el * 256, ln2b + el * 256);
    }

    // ---- pooling + Wout + weighted combine ----
    {
        #pragma unroll
        for (int ct = 0; ct < 4; ++ct) {
            float s_ = 0.f;
            #pragma unroll
            for (int rt = 0; rt < 2; ++rt)
                #pragma unroll
                for (int i = 0; i < 4; ++i) s_ += hr[rt * 4 + ct][i];
            s_ += __shfl_xor(s_, 16);
            s_ += __shfl_xor(s_, 32);
            if (quad == 0) pooledS[rh * 256 + nb + ct * 16 + ln] = s_;
        }
        __syncthreads();
        if (tid < 64) {
            const float* Wout_p = Wout + (size_t)e * (256 * 64);
            float o = bout[e * 64 + tid];
            for (int c = 0; c < 256; ++c)
                o += (pooledS[c] + pooledS[256 + c]) * (1.f / 64.f) * Wout_p[c * 64 + tid];
            atomicAdd(&acc_out[b * 64 + tid], wgt * o);
        }
    }
}

// ---------------------------------------------------------------------------
__global__ __launch_bounds__(64) void final_ln_kernel(
    const float* __restrict__ acc_out, const float* __restrict__ on_g,
    const float* __restrict__ on_b, float* __restrict__ out)
{
    const int b = blockIdx.x;
    const int d = threadIdx.x;
    float v = acc_out[b * 64 + d];
    float s1 = v, s2 = v * v;
    #pragma unroll
    for (int st = 1; st < 64; st <<= 1) {
        s1 += __shfl_xor(s1, st, 64);
        s2 += __shfl_xor(s2, st, 64);
    }
    float m   = s1 * (1.f / 64.f);
    float var = s2 * (1.f / 64.f) - m * m;
    float rstd = rsqrtf(var + 1e-5f);
    out[b * 64 + d] = (v - m) * rstd * on_g[d] + on_b[d];
}

// ---------------------------------------------------------------------------
extern "C" void kernel_launch(void* const* d_in, const int* in_sizes, int n_in,
                              void* d_out, int out_size, void* d_ws, size_t ws_size,
                              hipStream_t stream)
{
    (void)in_sizes; (void)n_in; (void)out_size; (void)ws_size;
    const float* x    = (const float*)d_in[0];
    const float* Win  = (const float*)d_in[1];
    const float* bin_ = (const float*)d_in[2];
    const float* Wq   = (const float*)d_in[3];
    const float* bq   = (const float*)d_in[4];
    const float* Wk   = (const float*)d_in[5];
    const float* bk   = (const float*)d_in[6];
    const float* Wv   = (const float*)d_in[7];
    const float* bv   = (const float*)d_in[8];
    const float* Wo   = (const float*)d_in[9];
    const float* bo   = (const float*)d_in[10];
    const float* ln1g = (const float*)d_in[11];
    const float* ln1b = (const float*)d_in[12];
    const float* ln2g = (const float*)d_in[13];
    const float* ln2b = (const float*)d_in[14];
    const float* W1   = (const float*)d_in[15];
    const float* b1   = (const float*)d_in[16];
    const float* W2   = (const float*)d_in[17];
    const float* b2   = (const float*)d_in[18];
    const float* Wout = (const float*)d_in[19];
    const float* bout = (const float*)d_in[20];
    const float* Wg   = (const float*)d_in[21];
    const float* bg   = (const float*)d_in[22];
    const float* Wr   = (const float*)d_in[23];
    const float* br   = (const float*)d_in[24];
    const float* on_g = (const float*)d_in[25];
    const float* on_b = (const float*)d_in[26];
    float* out = (float*)d_out;

    // workspace carve-up
    char* ws = (char*)d_ws;
    float* acc_out = (float*)ws;                         // 131,072 B
    int*   cnt     = (int*)(ws + 131072);
    int*   rlist   = (int*)(ws + 131200);                // 16,384 B
    float* wlist   = (float*)(ws + 147584);              // 16,384 B
    short* WinT    = (short*)(ws + 164096);              //   524,288 B
    short* WqT     = (short*)(ws + 688384);              // 2,097,152 B
    short* WkT     = (short*)(ws + 2785536);
    short* WvT     = (short*)(ws + 4882688);
    short* WoT     = (short*)(ws + 6979840);
    short* W1T     = (short*)(ws + 9076992);             // 8,388,608 B
    short* W2T     = (short*)(ws + 17465600);            // 8,388,608 B

    // weight transposition fp32 [R][C] -> bf16 [C][R]
    convT_kernel<<<1024, 256, 0, stream>>>(Win, WinT, 128, 256, 262144);
    convT_kernel<<<4096, 256, 0, stream>>>(Wq, WqT, 256, 256, 1048576);
    convT_kernel<<<4096, 256, 0, stream>>>(Wk, WkT, 256, 256, 1048576);
    convT_kernel<<<4096, 256, 0, stream>>>(Wv, WvT, 256, 256, 1048576);
    convT_kernel<<<4096, 256, 0, stream>>>(Wo, WoT, 256, 256, 1048576);
    convT_kernel<<<16384, 256, 0, stream>>>(W1, W1T, 256, 1024, 4194304);
    convT_kernel<<<16384, 256, 0, stream>>>(W2, W2T, 1024, 256, 4194304);

    zero_cnt_kernel<<<1, 64, 0, stream>>>(cnt);
    gate_kernel<<<512, 256, 0, stream>>>(x, Wg, bg, cnt, rlist, wlist);
    resproj_kernel<<<256, 256, 0, stream>>>(x, Wr, br, acc_out);
    expert_kernel<<<4096, 512, 0, stream>>>(x,
        WinT, bin_, WqT, bq, WkT, bk, WvT, bv, WoT, bo,
        ln1g, ln1b, ln2g, ln2b, W1T, b1, W2T, b2, Wout, bout,
        cnt, rlist, wlist, acc_out);
    final_ln_kernel<<<512, 64, 0, stream>>>(acc_out, on_g, on_b, out);
}